// Round 2
// baseline (131.695 us; speedup 1.0000x reference)
//
#include <hip/hip_runtime.h>

typedef __attribute__((ext_vector_type(8))) short bf16x8;
typedef __attribute__((ext_vector_type(16))) float f32x16;
typedef __attribute__((ext_vector_type(4))) unsigned int u32x4;

#define NH 8
#define CD 64
#define TLEN 1024
#define SENC 1024
#define STOT 2048
#define SK 64
#define NIT (STOT / SK)
#define BQ 64            // queries per block (2 waves x 32)
#define QSCALE 0.18033688f   // 0.125 * log2(e); fixed-scale softmax: any uniform
                             // scale on P cancels in (P.V)/sum(P), so no max needed

__device__ __forceinline__ ushort f2bf(float f) {
  uint x = __builtin_bit_cast(uint, f);
  uint r = (x + 0x7fffu + ((x >> 16) & 1u)) >> 16;
  return (ushort)r;
}
__device__ __forceinline__ uint4 pack8(const ushort* p) {
  uint4 u;
  u.x = (uint)p[0] | ((uint)p[1] << 16);
  u.y = (uint)p[2] | ((uint)p[3] << 16);
  u.z = (uint)p[4] | ((uint)p[5] << 16);
  u.w = (uint)p[6] | ((uint)p[7] << 16);
  return u;
}
// hw packed f32->bf16 (RNE), replaces ~8 VALU ops of software f2bf+pack
__device__ __forceinline__ uint cvtpk(float lo, float hi) {
  uint r;
  asm("v_cvt_pk_bf16_f32 %0, %1, %2" : "=v"(r) : "v"(lo), "v"(hi));
  return r;
}
// exchange a.hi32lanes <-> b.lo32lanes (CDNA4 v_permlane32_swap_b32)
__device__ __forceinline__ void plswap(uint& a, uint& b) {
  asm("v_permlane32_swap_b32 %0, %1" : "+v"(a), "+v"(b));
}
__device__ __forceinline__ bf16x8 mk8(uint a, uint b, uint c, uint d) {
  u32x4 t = {a, b, c, d};
  return __builtin_bit_cast(bf16x8, t);
}

// ---------------- pre-pass: cast K/V to bf16 in workspace (unchanged) --------
// z=0: Kt[bh][key][ci] (transposed via fp32 LDS tile), z=1: Vn[bh][ci][key]
__global__ __launch_bounds__(256)
void repack_kernel(const float* __restrict__ x, const float* __restrict__ ekv,
                   ushort* __restrict__ ktw, ushort* __restrict__ vnw) {
  const int kx = blockIdx.x;   // key tile 0..31 (64 keys each)
  const int bh = blockIdx.y;   // 0..31
  const int b = bh >> 3, h = bh & 7;
  const int t = threadIdx.x;
  const float* ks;
  const float* vs;
  if (kx < 16) {
    ks = ekv + (size_t)(b * 2 * NH * CD + h * CD) * SENC + kx * 64;
    vs = ekv + (size_t)(b * 2 * NH * CD + NH * CD + h * CD) * SENC + kx * 64;
  } else {
    ks = x + (size_t)(b * 3 * NH * CD + NH * CD + h * CD) * TLEN + (kx - 16) * 64;
    vs = x + (size_t)(b * 3 * NH * CD + 2 * NH * CD + h * CD) * TLEN + (kx - 16) * 64;
  }
  if (blockIdx.z == 0) {
    __shared__ float Lt[64 * 65];
    const int ci = t >> 2, seg = t & 3;
#pragma unroll
    for (int j = 0; j < 4; ++j) {
      float4 d = *(const float4*)&ks[ci * 1024 + seg * 16 + 4 * j];
      Lt[ci * 65 + seg * 16 + 4 * j + 0] = d.x;
      Lt[ci * 65 + seg * 16 + 4 * j + 1] = d.y;
      Lt[ci * 65 + seg * 16 + 4 * j + 2] = d.z;
      Lt[ci * 65 + seg * 16 + 4 * j + 3] = d.w;
    }
    __syncthreads();
    const int key = t >> 2;
    ushort tmp[16];
#pragma unroll
    for (int u = 0; u < 16; ++u)
      tmp[u] = f2bf(Lt[(seg * 16 + u) * 65 + key]);
    ushort* dst = ktw + ((size_t)bh * STOT + kx * 64 + key) * CD + seg * 16;
    *(uint4*)dst = pack8(tmp);
    *(uint4*)(dst + 8) = pack8(tmp + 8);
  } else {
    const int ci = t >> 2, seg = t & 3;
    ushort tmp[16];
#pragma unroll
    for (int j = 0; j < 4; ++j) {
      float4 d = *(const float4*)&vs[ci * 1024 + seg * 16 + 4 * j];
      tmp[4 * j + 0] = f2bf(d.x);
      tmp[4 * j + 1] = f2bf(d.y);
      tmp[4 * j + 2] = f2bf(d.z);
      tmp[4 * j + 3] = f2bf(d.w);
    }
    ushort* dst = vnw + (size_t)bh * CD * STOT + (size_t)ci * STOT + kx * 64 + seg * 16;
    *(uint4*)dst = pack8(tmp);
    *(uint4*)(dst + 8) = pack8(tmp + 8);
  }
}

// ---------------- main flash kernel: 32x32x16 MFMA, register-resident P ------
// 2 waves x 32 queries; S^T = K.Q^T so lane's query (l&31) is identical for
// S output, P fragments and O output -> P never touches LDS (cvt_pk + permlane).
// K/V tiles in LDS, rows of 64 bf16 (128B = 8 x 16B chunks), chunk index
// XOR-swizzled by (row&7) so all ds_read_b128 / ds_write_b128 hit the
// 8-bank-cycle minimum.
// Staging: 128 threads; each thread owns row tid>>1 and chunk half (tid&1)*4,
// i.e. 64B of K and 64B of V -> full 8KB K-tile + 8KB V-tile per iteration.
__global__ __launch_bounds__(128, 2)
void qkv_attn_ws(const float* __restrict__ x, const ushort* __restrict__ ktw,
                 const ushort* __restrict__ vnw, float* __restrict__ out) {
  __shared__ __align__(16) ushort Kb[2][SK * CD];   // [buf][key][ci]   8KB each
  __shared__ __align__(16) ushort Vb[2][CD * SK];   // [buf][ci][key]   8KB each

  const int tid  = threadIdx.x;
  const int w    = tid >> 6;        // wave 0..1
  const int lane = tid & 63;
  const int al   = lane & 31;       // m/n index within 32-wide MFMA tile
  const int h    = lane >> 5;       // k-half selector
  const int xm   = lane & 7;        // swizzle mask (== row&7 for rows mt*32+al)

  // XCD swizzle: all 16 query-tiles of one bh land on one XCD (id = f%8)
  const int f  = blockIdx.x;
  const int bh = (f & 7) | ((f >> 7) << 3);
  const int qt = (f >> 3) & 15;
  const int b  = bh >> 3;
  const int hh = bh & 7;
  const int t0 = qt * BQ;

  const float* qg = x + (size_t)(b * 3 * NH * CD + hh * CD) * TLEN;
  float* og = out + (size_t)(b * NH * CD + hh * CD) * TLEN;
  const ushort* ktb = ktw + (size_t)bh * STOT * CD;   // [key][ci]
  const ushort* vnb = vnw + (size_t)bh * CD * STOT;   // [ci][key]

  // ---- staging geometry: each thread stages 64B K + 64B V, swizzled
  const int srow = tid >> 1;                 // 0..63 (key row / ci row)
  const int cb   = (tid & 1) * 4;            // chunk base: 0 or 4 (16B chunks)
  int swz[4];
#pragma unroll
  for (int j = 0; j < 4; ++j) swz[j] = (((cb + j) ^ (srow & 7)) * 8);

  // ---- prologue: load chunk 0 into regs, store swizzled into buf 0
  uint4 kp[4], vp[4];
#pragma unroll
  for (int j = 0; j < 4; ++j) {
    kp[j] = *(const uint4*)(ktb + (size_t)srow * CD + (cb + j) * 8);
    vp[j] = *(const uint4*)(vnb + (size_t)srow * STOT + (cb + j) * 8);
  }
#pragma unroll
  for (int j = 0; j < 4; ++j) {
    *(uint4*)&Kb[0][srow * CD + swz[j]] = kp[j];
    *(uint4*)&Vb[0][srow * CD + swz[j]] = vp[j];
  }

  // ---- Q direct to registers (no LDS): B-frag n = w*32+al, k(ci) = kst*16+h*8+j
  const int q_l = w * 32 + al;
  const float* qp = qg + t0 + q_l;
  float qv[4][8];
#pragma unroll
  for (int kst = 0; kst < 4; ++kst)
#pragma unroll
    for (int j = 0; j < 8; ++j)
      qv[kst][j] = qp[(size_t)(kst * 16 + h * 8 + j) * TLEN] * QSCALE;
  bf16x8 qfrag[4];
#pragma unroll
  for (int kst = 0; kst < 4; ++kst)
    qfrag[kst] = mk8(cvtpk(qv[kst][0], qv[kst][1]), cvtpk(qv[kst][2], qv[kst][3]),
                     cvtpk(qv[kst][4], qv[kst][5]), cvtpk(qv[kst][6], qv[kst][7]));

  __syncthreads();   // buf 0 staged

  // per-lane swizzled read offsets (row&7 == xm for all rows we read)
  int koff[4];
#pragma unroll
  for (int kst = 0; kst < 4; ++kst) koff[kst] = ((2 * kst + h) ^ xm) * 8;

  f32x16 of0, of1;
#pragma unroll
  for (int i = 0; i < 16; ++i) { of0[i] = 0.f; of1[i] = 0.f; }
  float l_acc = 0.f;   // softmax denom partial (query q_l; this h-half's keys)

  for (int it = 0; it < NIT; ++it) {
    const int cur = it & 1;

    // ---- issue next chunk's global loads first (overlap with compute)
    if (it + 1 < NIT) {
      const int s1 = (it + 1) * SK;
#pragma unroll
      for (int j = 0; j < 4; ++j) {
        kp[j] = *(const uint4*)(ktb + (size_t)(s1 + srow) * CD + (cb + j) * 8);
        vp[j] = *(const uint4*)(vnb + (size_t)srow * STOT + s1 + (cb + j) * 8);
      }
    }

    const ushort* kt = Kb[cur];
    const ushort* vt = Vb[cur];

    // ---- S^T = K.Q^T : A=K rows (m=key mt*32+al), B=Q; D col=q(al),
    // row=key=(reg&3)+8*(reg>>2)+4h. p = exp2(s); fixed scale cancels in O/l.
    uint ulo[8], uhi[8];   // packed bf16 P pairs, chunk c=4*mt+rq (keys 8c+4h+0..3)
#pragma unroll
    for (int mt = 0; mt < 2; ++mt) {
      f32x16 acc;
#pragma unroll
      for (int i = 0; i < 16; ++i) acc[i] = 0.f;
#pragma unroll
      for (int kst = 0; kst < 4; ++kst) {
        bf16x8 afr = *(const bf16x8*)&kt[(mt * 32 + al) * CD + koff[kst]];
        acc = __builtin_amdgcn_mfma_f32_32x32x16_bf16(afr, qfrag[kst], acc, 0, 0, 0);
      }
#pragma unroll
      for (int rq = 0; rq < 4; ++rq) {
        float p0 = exp2f(acc[4 * rq + 0]);
        float p1 = exp2f(acc[4 * rq + 1]);
        float p2 = exp2f(acc[4 * rq + 2]);
        float p3 = exp2f(acc[4 * rq + 3]);
        l_acc += (p0 + p1) + (p2 + p3);
        ulo[4 * mt + rq] = cvtpk(p0, p1);
        uhi[4 * mt + rq] = cvtpk(p2, p3);
      }
    }

    // ---- build PV B-frags in-register: lane pair (l, l^32) holds the two
    // key-half chunks; v_permlane32_swap (a.hi<->b.lo) completes each chunk.
    // pfr[kst] = P^T[key=kst*16+h*8+j][q=al]
    bf16x8 pfr[4];
#pragma unroll
    for (int kst = 0; kst < 4; ++kst) {
      uint xlo = ulo[2 * kst], ylo = ulo[2 * kst + 1];
      uint xhi = uhi[2 * kst], yhi = uhi[2 * kst + 1];
      plswap(xlo, ylo);
      plswap(xhi, yhi);
      pfr[kst] = mk8(xlo, xhi, ylo, yhi);
    }

    // ---- O^T += V.P^T : A=V rows (m=ci mtc*32+al)
#pragma unroll
    for (int kst = 0; kst < 4; ++kst) {
      bf16x8 v0 = *(const bf16x8*)&vt[(0 * 32 + al) * CD + koff[kst]];
      bf16x8 v1 = *(const bf16x8*)&vt[(1 * 32 + al) * CD + koff[kst]];
      of0 = __builtin_amdgcn_mfma_f32_32x32x16_bf16(v0, pfr[kst], of0, 0, 0, 0);
      of1 = __builtin_amdgcn_mfma_f32_32x32x16_bf16(v1, pfr[kst], of1, 0, 0, 0);
    }

    // ---- stage prefetched chunk; single barrier per iter
    if (it + 1 < NIT) {
      const int nb = cur ^ 1;
#pragma unroll
      for (int j = 0; j < 4; ++j) {
        *(uint4*)&Kb[nb][srow * CD + swz[j]] = kp[j];
        *(uint4*)&Vb[nb][srow * CD + swz[j]] = vp[j];
      }
      __syncthreads();
    }
  }

  // ---- epilogue: l = own half + partner half (same query on l^32); divide, store
  {
    float lv = l_acc + __shfl_xor(l_acc, 32);
    float inv = 1.0f / lv;
    float* ob = og + t0 + q_l;
#pragma unroll
    for (int r = 0; r < 16; ++r) {
      int ci = (r & 3) + 8 * (r >> 2) + 4 * h;
      ob[(size_t)ci * TLEN] = of0[r] * inv;              // coalesced across al
      ob[(size_t)(32 + ci) * TLEN] = of1[r] * inv;
    }
  }
}

extern "C" void kernel_launch(void* const* d_in, const int* in_sizes, int n_in,
                              void* d_out, int out_size, void* d_ws, size_t ws_size,
                              hipStream_t stream) {
  const float* x   = (const float*)d_in[0];   // (4, 1536, 1024) fp32
  const float* ekv = (const float*)d_in[1];   // (4, 1024, 1024) fp32
  float* out = (float*)d_out;                 // (4, 512, 1024) fp32
  ushort* ktw = (ushort*)d_ws;
  ushort* vnw = ktw + (size_t)32 * STOT * CD;
  repack_kernel<<<dim3(32, 32, 2), 256, 0, stream>>>(x, ekv, ktw, vnw);
  qkv_attn_ws<<<512, 128, 0, stream>>>(x, ktw, vnw, out);
}

// Round 3
// 120.555 us; speedup vs baseline: 1.0924x; 1.0924x over previous
//
#include <hip/hip_runtime.h>

typedef __attribute__((ext_vector_type(8))) short bf16x8;
typedef __attribute__((ext_vector_type(16))) float f32x16;
typedef __attribute__((ext_vector_type(4))) float f32x4;
typedef __attribute__((ext_vector_type(4))) unsigned int u32x4;

#define NH 8
#define CD 64
#define TLEN 1024
#define SENC 1024
#define STOT 2048
#define SK 64
#define NSPLIT 2                 // key splits (flash-decoding style)
#define SKEYS (STOT / NSPLIT)    // 1024 keys per block
#define NITS (SKEYS / SK)        // 16 iters per block
#define BQ 64                    // queries per block (2 waves x 32)
#define QSCALE 0.18033688f   // 0.125 * log2(e); fixed-scale softmax: any uniform
                             // scale on P cancels in (P.V)/sum(P), so no max
                             // needed, and split partials add directly.

__device__ __forceinline__ ushort f2bf(float f) {
  uint x = __builtin_bit_cast(uint, f);
  uint r = (x + 0x7fffu + ((x >> 16) & 1u)) >> 16;
  return (ushort)r;
}
__device__ __forceinline__ uint4 pack8(const ushort* p) {
  uint4 u;
  u.x = (uint)p[0] | ((uint)p[1] << 16);
  u.y = (uint)p[2] | ((uint)p[3] << 16);
  u.z = (uint)p[4] | ((uint)p[5] << 16);
  u.w = (uint)p[6] | ((uint)p[7] << 16);
  return u;
}
// hw packed f32->bf16 (RNE)
__device__ __forceinline__ uint cvtpk(float lo, float hi) {
  uint r;
  asm("v_cvt_pk_bf16_f32 %0, %1, %2" : "=v"(r) : "v"(lo), "v"(hi));
  return r;
}
// exchange a.hi32lanes <-> b.lo32lanes (CDNA4 v_permlane32_swap_b32)
__device__ __forceinline__ void plswap(uint& a, uint& b) {
  asm("v_permlane32_swap_b32 %0, %1" : "+v"(a), "+v"(b));
}
__device__ __forceinline__ bf16x8 mk8(uint a, uint b, uint c, uint d) {
  u32x4 t = {a, b, c, d};
  return __builtin_bit_cast(bf16x8, t);
}

// ---------------- pre-pass: cast K/V to bf16 in workspace (unchanged) --------
// z=0: Kt[bh][key][ci] (transposed via fp32 LDS tile), z=1: Vn[bh][ci][key]
__global__ __launch_bounds__(256)
void repack_kernel(const float* __restrict__ x, const float* __restrict__ ekv,
                   ushort* __restrict__ ktw, ushort* __restrict__ vnw) {
  const int kx = blockIdx.x;   // key tile 0..31 (64 keys each)
  const int bh = blockIdx.y;   // 0..31
  const int b = bh >> 3, h = bh & 7;
  const int t = threadIdx.x;
  const float* ks;
  const float* vs;
  if (kx < 16) {
    ks = ekv + (size_t)(b * 2 * NH * CD + h * CD) * SENC + kx * 64;
    vs = ekv + (size_t)(b * 2 * NH * CD + NH * CD + h * CD) * SENC + kx * 64;
  } else {
    ks = x + (size_t)(b * 3 * NH * CD + NH * CD + h * CD) * TLEN + (kx - 16) * 64;
    vs = x + (size_t)(b * 3 * NH * CD + 2 * NH * CD + h * CD) * TLEN + (kx - 16) * 64;
  }
  if (blockIdx.z == 0) {
    __shared__ float Lt[64 * 65];
    const int ci = t >> 2, seg = t & 3;
#pragma unroll
    for (int j = 0; j < 4; ++j) {
      float4 d = *(const float4*)&ks[ci * 1024 + seg * 16 + 4 * j];
      Lt[ci * 65 + seg * 16 + 4 * j + 0] = d.x;
      Lt[ci * 65 + seg * 16 + 4 * j + 1] = d.y;
      Lt[ci * 65 + seg * 16 + 4 * j + 2] = d.z;
      Lt[ci * 65 + seg * 16 + 4 * j + 3] = d.w;
    }
    __syncthreads();
    const int key = t >> 2;
    ushort tmp[16];
#pragma unroll
    for (int u = 0; u < 16; ++u)
      tmp[u] = f2bf(Lt[(seg * 16 + u) * 65 + key]);
    ushort* dst = ktw + ((size_t)bh * STOT + kx * 64 + key) * CD + seg * 16;
    *(uint4*)dst = pack8(tmp);
    *(uint4*)(dst + 8) = pack8(tmp + 8);
  } else {
    const int ci = t >> 2, seg = t & 3;
    ushort tmp[16];
#pragma unroll
    for (int j = 0; j < 4; ++j) {
      float4 d = *(const float4*)&vs[ci * 1024 + seg * 16 + 4 * j];
      tmp[4 * j + 0] = f2bf(d.x);
      tmp[4 * j + 1] = f2bf(d.y);
      tmp[4 * j + 2] = f2bf(d.z);
      tmp[4 * j + 3] = f2bf(d.w);
    }
    ushort* dst = vnw + (size_t)bh * CD * STOT + (size_t)ci * STOT + kx * 64 + seg * 16;
    *(uint4*)dst = pack8(tmp);
    *(uint4*)(dst + 8) = pack8(tmp + 8);
  }
}

// ---------------- main flash kernel: 32x32x16 MFMA, register P, split-K ------
// Grid: 32 bh x 16 qt x NSPLIT key-splits = 1024 blocks x 2 waves
//   -> 8 waves/CU = 2/SIMD (double round-2's occupancy; the measured limit).
// Each block processes SKEYS keys and writes UNNORMALIZED O-partial (f32) + l.
// Fixed-scale softmax => partials combine by simple addition.
__global__ __launch_bounds__(128, 2)
void qkv_attn_ws(const float* __restrict__ x, const ushort* __restrict__ ktw,
                 const ushort* __restrict__ vnw, float* __restrict__ po,
                 float* __restrict__ lw) {
  __shared__ __align__(16) ushort Kb[2][SK * CD];   // [buf][key][ci]   8KB each
  __shared__ __align__(16) ushort Vb[2][CD * SK];   // [buf][ci][key]   8KB each

  const int tid  = threadIdx.x;
  const int w    = tid >> 6;        // wave 0..1
  const int lane = tid & 63;
  const int al   = lane & 31;       // m/n index within 32-wide MFMA tile
  const int h    = lane >> 5;       // k-half selector
  const int xm   = lane & 7;        // swizzle mask (== row&7 for rows mt*32+al)

  // XCD swizzle: all 32 (qt,ks) tiles of one bh land on one XCD (id = f%8)
  // bits: [2:0]=bh_lo, [6:3]=qt, [7]=ks, [9:8]=bh_hi  (bijective on 0..1023)
  const int f  = blockIdx.x;
  const int bh = (f & 7) | (((f >> 8) & 3) << 3);
  const int qt = (f >> 3) & 15;
  const int ks = (f >> 7) & 1;
  const int b  = bh >> 3;
  const int hh = bh & 7;
  const int t0 = qt * BQ;
  const int kbase = ks * SKEYS;

  const float* qg = x + (size_t)(b * 3 * NH * CD + hh * CD) * TLEN;
  const ushort* ktb = ktw + (size_t)bh * STOT * CD;   // [key][ci]
  const ushort* vnb = vnw + (size_t)bh * CD * STOT;   // [ci][key]
  float* pob = po + ((size_t)ks * 32 + bh) * CD * TLEN;
  float* lwb = lw + ((size_t)ks * 32 + bh) * TLEN;

  // ---- staging geometry: each thread stages 64B K + 64B V, swizzled
  const int srow = tid >> 1;                 // 0..63 (key row / ci row)
  const int cb   = (tid & 1) * 4;            // chunk base: 0 or 4 (16B chunks)
  int swz[4];
#pragma unroll
  for (int j = 0; j < 4; ++j) swz[j] = (((cb + j) ^ (srow & 7)) * 8);

  // ---- prologue: load chunk 0 into regs, store swizzled into buf 0
  uint4 kp[4], vp[4];
#pragma unroll
  for (int j = 0; j < 4; ++j) {
    kp[j] = *(const uint4*)(ktb + (size_t)(kbase + srow) * CD + (cb + j) * 8);
    vp[j] = *(const uint4*)(vnb + (size_t)srow * STOT + kbase + (cb + j) * 8);
  }
#pragma unroll
  for (int j = 0; j < 4; ++j) {
    *(uint4*)&Kb[0][srow * CD + swz[j]] = kp[j];
    *(uint4*)&Vb[0][srow * CD + swz[j]] = vp[j];
  }

  // ---- Q direct to registers (no LDS): B-frag n = w*32+al, k(ci) = kst*16+h*8+j
  const int q_l = w * 32 + al;
  const float* qp = qg + t0 + q_l;
  float qv[4][8];
#pragma unroll
  for (int kst = 0; kst < 4; ++kst)
#pragma unroll
    for (int j = 0; j < 8; ++j)
      qv[kst][j] = qp[(size_t)(kst * 16 + h * 8 + j) * TLEN] * QSCALE;
  bf16x8 qfrag[4];
#pragma unroll
  for (int kst = 0; kst < 4; ++kst)
    qfrag[kst] = mk8(cvtpk(qv[kst][0], qv[kst][1]), cvtpk(qv[kst][2], qv[kst][3]),
                     cvtpk(qv[kst][4], qv[kst][5]), cvtpk(qv[kst][6], qv[kst][7]));

  __syncthreads();   // buf 0 staged

  // per-lane swizzled read offsets (row&7 == xm for all rows we read)
  int koff[4];
#pragma unroll
  for (int kst = 0; kst < 4; ++kst) koff[kst] = ((2 * kst + h) ^ xm) * 8;

  f32x16 of0, of1;
#pragma unroll
  for (int i = 0; i < 16; ++i) { of0[i] = 0.f; of1[i] = 0.f; }
  float l_acc = 0.f;   // softmax denom partial (query q_l; this h-half's keys)

  for (int it = 0; it < NITS; ++it) {
    const int cur = it & 1;

    // ---- issue next chunk's global loads first (overlap with compute)
    if (it + 1 < NITS) {
      const int s1 = kbase + (it + 1) * SK;
#pragma unroll
      for (int j = 0; j < 4; ++j) {
        kp[j] = *(const uint4*)(ktb + (size_t)(s1 + srow) * CD + (cb + j) * 8);
        vp[j] = *(const uint4*)(vnb + (size_t)srow * STOT + s1 + (cb + j) * 8);
      }
    }

    const ushort* kt = Kb[cur];
    const ushort* vt = Vb[cur];

    // ---- S^T = K.Q^T : A=K rows (m=key mt*32+al), B=Q; D col=q(al),
    // row=key=(reg&3)+8*(reg>>2)+4h. p = exp2(s); fixed scale cancels in O/l.
    uint ulo[8], uhi[8];   // packed bf16 P pairs, chunk c=4*mt+rq (keys 8c+4h+0..3)
#pragma unroll
    for (int mt = 0; mt < 2; ++mt) {
      f32x16 acc;
#pragma unroll
      for (int i = 0; i < 16; ++i) acc[i] = 0.f;
#pragma unroll
      for (int kst = 0; kst < 4; ++kst) {
        bf16x8 afr = *(const bf16x8*)&kt[(mt * 32 + al) * CD + koff[kst]];
        acc = __builtin_amdgcn_mfma_f32_32x32x16_bf16(afr, qfrag[kst], acc, 0, 0, 0);
      }
#pragma unroll
      for (int rq = 0; rq < 4; ++rq) {
        float p0 = exp2f(acc[4 * rq + 0]);
        float p1 = exp2f(acc[4 * rq + 1]);
        float p2 = exp2f(acc[4 * rq + 2]);
        float p3 = exp2f(acc[4 * rq + 3]);
        l_acc += (p0 + p1) + (p2 + p3);
        ulo[4 * mt + rq] = cvtpk(p0, p1);
        uhi[4 * mt + rq] = cvtpk(p2, p3);
      }
    }

    // ---- build PV B-frags in-register: lane pair (l, l^32) holds the two
    // key-half chunks; v_permlane32_swap (a.hi<->b.lo) completes each chunk.
    // pfr[kst] = P^T[key=kst*16+h*8+j][q=al]
    bf16x8 pfr[4];
#pragma unroll
    for (int kst = 0; kst < 4; ++kst) {
      uint xlo = ulo[2 * kst], ylo = ulo[2 * kst + 1];
      uint xhi = uhi[2 * kst], yhi = uhi[2 * kst + 1];
      plswap(xlo, ylo);
      plswap(xhi, yhi);
      pfr[kst] = mk8(xlo, xhi, ylo, yhi);
    }

    // ---- O^T += V.P^T : A=V rows (m=ci mtc*32+al)
#pragma unroll
    for (int kst = 0; kst < 4; ++kst) {
      bf16x8 v0 = *(const bf16x8*)&vt[(0 * 32 + al) * CD + koff[kst]];
      bf16x8 v1 = *(const bf16x8*)&vt[(1 * 32 + al) * CD + koff[kst]];
      of0 = __builtin_amdgcn_mfma_f32_32x32x16_bf16(v0, pfr[kst], of0, 0, 0, 0);
      of1 = __builtin_amdgcn_mfma_f32_32x32x16_bf16(v1, pfr[kst], of1, 0, 0, 0);
    }

    // ---- stage prefetched chunk; single barrier per iter
    if (it + 1 < NITS) {
      const int nb = cur ^ 1;
#pragma unroll
      for (int j = 0; j < 4; ++j) {
        *(uint4*)&Kb[nb][srow * CD + swz[j]] = kp[j];
        *(uint4*)&Vb[nb][srow * CD + swz[j]] = vp[j];
      }
      __syncthreads();
    }
  }

  // ---- epilogue: write UNNORMALIZED O-partial + l-partial (combine divides)
  {
    float lv = l_acc + __shfl_xor(l_acc, 32);
    float* ob = pob + t0 + q_l;
#pragma unroll
    for (int r = 0; r < 16; ++r) {
      int ci = (r & 3) + 8 * (r >> 2) + 4 * h;
      ob[(size_t)ci * TLEN] = of0[r];                 // coalesced f32 across al
      ob[(size_t)(32 + ci) * TLEN] = of1[r];
    }
    if (h == 0) lwb[t0 + q_l] = lv;
  }
}

// ---------------- combine: out = (O0+O1) / (l0+l1) ---------------------------
// 2M outputs, 8 f32/thread; l rows L2-cached (reused by 64 ci rows per bh).
__global__ __launch_bounds__(256)
void combine_kernel(const float* __restrict__ po, const float* __restrict__ lw,
                    float* __restrict__ out) {
  const int idx = blockIdx.x * 256 + threadIdx.x;   // 0..262143
  const int row = idx >> 7;          // bh*64+ci (0..2047)
  const int t8  = (idx & 127) * 8;   // t base
  const int bh  = row >> 6;
  const size_t KSS = (size_t)32 * CD * TLEN;        // po split stride
  const float* p0 = po + (size_t)row * TLEN + t8;
  const float* p1 = p0 + KSS;
  const float* l0 = lw + (size_t)bh * TLEN + t8;
  const float* l1 = l0 + (size_t)32 * TLEN;
  f32x4 a0 = *(const f32x4*)p0,       a1 = *(const f32x4*)(p0 + 4);
  f32x4 b0 = *(const f32x4*)p1,       b1 = *(const f32x4*)(p1 + 4);
  f32x4 u0 = *(const f32x4*)l0,       u1 = *(const f32x4*)(l0 + 4);
  f32x4 v0 = *(const f32x4*)l1,       v1 = *(const f32x4*)(l1 + 4);
  f32x4 r0 = (a0 + b0) / (u0 + v0);
  f32x4 r1 = (a1 + b1) / (u1 + v1);
  float* o = out + (size_t)row * TLEN + t8;
  *(f32x4*)o = r0;
  *(f32x4*)(o + 4) = r1;
}

extern "C" void kernel_launch(void* const* d_in, const int* in_sizes, int n_in,
                              void* d_out, int out_size, void* d_ws, size_t ws_size,
                              hipStream_t stream) {
  const float* x   = (const float*)d_in[0];   // (4, 1536, 1024) fp32
  const float* ekv = (const float*)d_in[1];   // (4, 1024, 1024) fp32
  float* out = (float*)d_out;                 // (4, 512, 1024) fp32
  // workspace layout: ktw 8MB | vnw 8MB | po 16MB | lw 256KB  (32.25MB total)
  ushort* ktw = (ushort*)d_ws;
  ushort* vnw = ktw + (size_t)32 * STOT * CD;
  float*  po  = (float*)(vnw + (size_t)32 * STOT * CD);
  float*  lw  = po + (size_t)NSPLIT * 32 * CD * TLEN;
  repack_kernel<<<dim3(32, 32, 2), 256, 0, stream>>>(x, ekv, ktw, vnw);
  qkv_attn_ws<<<32 * 16 * NSPLIT, 128, 0, stream>>>(x, ktw, vnw, po, lw);
  combine_kernel<<<1024, 256, 0, stream>>>(po, lw, out);
}